// Round 3
// baseline (224.604 us; speedup 1.0000x reference)
//
#include <hip/hip_runtime.h>

// ---------------------------------------------------------------------------
// GuidedAttentionL1Loss on MI355X — R2: single fused kernel.
// loss = nll + (ALPHA/2)*sum|params| + (BETA/2)*mean_b( sum_b (y-r)^2 / L_b )
// sum(y-r)^2 = sum y^2 - 2*sum(y*rh)/den + sum(rh^2)/den^2, den = sum(rh)+1e-6
// Changes vs R1: float4 single-pass attn read with y held in registers,
// per-wave int4 scan for starts (no scan kernel), whole problem fused into
// one kernel with completion-counter finalize (2 graph nodes total).
// ---------------------------------------------------------------------------

constexpr float INV_SQRT_2PI = 0.39894228040143267794f;
constexpr int L1_BLOCKS = 64;

// ws layout (bytes):
//   0:    unsigned counter            (memset to 0 each launch)
//   512:  double nllsum
//   1024: float l1part[64*16]         (stride 16 floats = 64B line per block)
//   8192: float segpart[segBlocks*16] (4 slots used per block, 64B/block)

__global__ __launch_bounds__(256) void fused_kernel(
    const float* __restrict__ logits, const float* __restrict__ params,
    const float* __restrict__ attn, const int* __restrict__ labels,
    const int* __restrict__ lengths, int P, int Bn, int segBlocks,
    unsigned* __restrict__ counter, double* __restrict__ nllsum,
    float* __restrict__ l1part, float* __restrict__ segpart,
    float* __restrict__ out) {
  const int tid = threadIdx.x, lane = tid & 63, wv = tid >> 6;
  const int bid = blockIdx.x;
  __shared__ int s_last;
  __shared__ double s_redA[4], s_redB[4];
  __shared__ float s_l1[4];

  if (bid < segBlocks) {
    // ---------------- per-segment penalty: one wave per segment -------------
    int wid = (bid << 2) + wv;
    if (wid < Bn) {
      // exclusive start = sum lengths[0..wid) via int4 mini-scan (L1-resident)
      int start = 0;
      const int4* l4 = (const int4*)lengths;
      int nq = wid >> 2;
      for (int q = lane; q < nq; q += 64) {
        int4 v = l4[q];
        start += (v.x + v.y) + (v.z + v.w);
      }
      if (lane < (wid & 3)) start += lengths[(wid & ~3) + lane];
#pragma unroll
      for (int off = 32; off; off >>= 1) start += __shfl_xor(start, off, 64);

      int L = lengths[wid];
      const float* a = attn + start;
      float invL = 1.0f / (float)L;
      int head = (4 - (start & 3)) & 3;   // peel to 16B alignment
      if (head > L) head = L;
      int nb = (L - head) >> 2;           // aligned float4 quads (<= 768)
      int tail = L - head - (nb << 2);
      const float4* a4 = (const float4*)(a + head);

      // ---- single HBM pass: load y into registers, moments of y ----
      float sy = 0.f, sxy = 0.f, syy = 0.f;
      float yh = 0.f, yt = 0.f;
      int ih = -1, it = -1;
      if (lane < head) {
        ih = lane; yh = a[ih];
        float x = (float)(ih + 1) * invL;
        sy += yh; sxy = fmaf(x, yh, sxy); syy = fmaf(yh, yh, syy);
      }
      if (lane < tail) {
        it = head + (nb << 2) + lane; yt = a[it];
        float x = (float)(it + 1) * invL;
        sy += yt; sxy = fmaf(x, yt, sxy); syy = fmaf(yt, yt, syy);
      }
      float4 yv[12];
#pragma unroll
      for (int k = 0; k < 12; ++k) {
        int q = k * 64 + lane;
        if (q < nb) {
          float4 v = a4[q];
          yv[k] = v;
          int i0 = head + (q << 2);
          float x0 = (float)(i0 + 1) * invL;
          float x1 = (float)(i0 + 2) * invL;
          float x2 = (float)(i0 + 3) * invL;
          float x3 = (float)(i0 + 4) * invL;
          sy += (v.x + v.y) + (v.z + v.w);
          sxy = fmaf(x0, v.x, fmaf(x1, v.y, fmaf(x2, v.z, fmaf(x3, v.w, sxy))));
          syy = fmaf(v.x, v.x, fmaf(v.y, v.y, fmaf(v.z, v.z, fmaf(v.w, v.w, syy))));
        } else {
          yv[k] = make_float4(0.f, 0.f, 0.f, 0.f);
        }
      }
#pragma unroll
      for (int off = 32; off; off >>= 1) {
        sy  += __shfl_xor(sy, off, 64);
        sxy += __shfl_xor(sxy, off, 64);
      }
      float mean = sxy / sy;
      float inv_std = (labels[wid] == 1) ? (float)L : (float)L * 0.001f;
      float inv_norm = INV_SQRT_2PI * inv_std;

      // ---- pass B: register-only (recompute rh, y from regs) ----
      float sr = 0.f, syr = 0.f, srr = 0.f;
      if (ih >= 0) {
        float z = ((float)(ih + 1) * invL - mean) * inv_std;
        float r = expf(-0.5f * z * z) * inv_norm;
        sr += r; syr = fmaf(yh, r, syr); srr = fmaf(r, r, srr);
      }
      if (it >= 0) {
        float z = ((float)(it + 1) * invL - mean) * inv_std;
        float r = expf(-0.5f * z * z) * inv_norm;
        sr += r; syr = fmaf(yt, r, syr); srr = fmaf(r, r, srr);
      }
#pragma unroll
      for (int k = 0; k < 12; ++k) {
        int q = k * 64 + lane;
        if (q < nb) {
          int i0 = head + (q << 2);
          float4 v = yv[k];
          float z0 = ((float)(i0 + 1) * invL - mean) * inv_std;
          float z1 = ((float)(i0 + 2) * invL - mean) * inv_std;
          float z2 = ((float)(i0 + 3) * invL - mean) * inv_std;
          float z3 = ((float)(i0 + 4) * invL - mean) * inv_std;
          float r0 = expf(-0.5f * z0 * z0) * inv_norm;
          float r1 = expf(-0.5f * z1 * z1) * inv_norm;
          float r2 = expf(-0.5f * z2 * z2) * inv_norm;
          float r3 = expf(-0.5f * z3 * z3) * inv_norm;
          sr += (r0 + r1) + (r2 + r3);
          syr = fmaf(v.x, r0, fmaf(v.y, r1, fmaf(v.z, r2, fmaf(v.w, r3, syr))));
          srr = fmaf(r0, r0, fmaf(r1, r1, fmaf(r2, r2, fmaf(r3, r3, srr))));
        }
      }
#pragma unroll
      for (int off = 32; off; off >>= 1) {
        syy += __shfl_xor(syy, off, 64);
        sr  += __shfl_xor(sr, off, 64);
        syr += __shfl_xor(syr, off, 64);
        srr += __shfl_xor(srr, off, 64);
      }
      if (lane == 0) {
        float inv_den = 1.0f / (sr + 1e-6f);
        float d2 = syy - 2.0f * syr * inv_den + srr * (inv_den * inv_den);
        segpart[(bid << 4) + wv] = d2 * invL;
      }
    }
  } else if (bid < segBlocks + L1_BLOCKS) {
    // ---------------- L1: sum |params| --------------------------------------
    int b = bid - segBlocks;
    const float4* p4 = (const float4*)params;
    int n4 = P >> 2;
    float s = 0.f;
    for (int i = (b << 8) + tid; i < n4; i += (L1_BLOCKS << 8)) {
      float4 v = p4[i];
      s += (fabsf(v.x) + fabsf(v.y)) + (fabsf(v.z) + fabsf(v.w));
    }
    if (b == 0) {  // generic tail (empty for P % 4 == 0)
      for (int i = (n4 << 2) + tid; i < P; i += 256) s += fabsf(params[i]);
    }
#pragma unroll
    for (int off = 32; off; off >>= 1) s += __shfl_xor(s, off, 64);
    if (lane == 0) s_l1[wv] = s;
    __syncthreads();
    if (tid == 0) l1part[b << 4] = (s_l1[0] + s_l1[1]) + (s_l1[2] + s_l1[3]);
  } else {
    // ---------------- NLL ---------------------------------------------------
    double s = 0.0;
    const float2* lg2 = (const float2*)logits;
    for (int r = tid; r < Bn; r += 256) {
      float2 lg = lg2[r];
      float m = fmaxf(lg.x, lg.y);
      float lse = m + logf(expf(lg.x - m) + expf(lg.y - m));
      s += (double)(lse - ((labels[r] == 1) ? lg.y : lg.x));
    }
#pragma unroll
    for (int off = 32; off; off >>= 1) s += __shfl_down(s, off, 64);
    if (lane == 0) s_redA[wv] = s;
    __syncthreads();
    if (tid == 0) *nllsum = (s_redA[0] + s_redA[1]) + (s_redA[2] + s_redA[3]);
  }

  // ---------------- completion counter; last block finalizes ----------------
  __threadfence();
  __syncthreads();
  if (tid == 0) {
    unsigned old = atomicAdd(counter, 1u);
    s_last = (old == gridDim.x - 1) ? 1 : 0;
  }
  __syncthreads();
  if (s_last) {
    __threadfence();
    double accS = 0.0;
    for (int j = tid; j < Bn; j += 256)
      accS += (double)segpart[((j >> 2) << 4) + (j & 3)];
    double accL = (tid < L1_BLOCKS) ? (double)l1part[tid << 4] : 0.0;
#pragma unroll
    for (int off = 32; off; off >>= 1) {
      accS += __shfl_down(accS, off, 64);
      accL += __shfl_down(accL, off, 64);
    }
    if (lane == 0) { s_redA[wv] = accS; s_redB[wv] = accL; }
    __syncthreads();
    if (tid == 0) {
      double segsum = (s_redA[0] + s_redA[1]) + (s_redA[2] + s_redA[3]);
      double l1 = (s_redB[0] + s_redB[1]) + (s_redB[2] + s_redB[3]);
      double nll = *nllsum / (double)Bn;
      double loss = nll + 5e-4 * l1 + 0.05 * (segsum / (double)Bn);
      out[0] = (float)loss;
      out[1] = (float)nll;
    }
  }
}

extern "C" void kernel_launch(void* const* d_in, const int* in_sizes, int n_in,
                              void* d_out, int out_size, void* d_ws, size_t ws_size,
                              hipStream_t stream) {
  const float* logits  = (const float*)d_in[0];
  const float* params  = (const float*)d_in[1];
  const float* attn    = (const float*)d_in[2];
  const int*   labels  = (const int*)d_in[3];
  const int*   lengths = (const int*)d_in[4];
  // d_in[5] (seg_ids) unused: starts recomputed from lengths.

  int Bn = in_sizes[3];
  int P  = in_sizes[1];
  int segBlocks = (Bn + 3) / 4;

  unsigned* counter = (unsigned*)d_ws;
  double*   nllsum  = (double*)((char*)d_ws + 512);
  float*    l1part  = (float*)((char*)d_ws + 1024);
  float*    segpart = (float*)((char*)d_ws + 8192);

  hipMemsetAsync(d_ws, 0, 64, stream);  // zero completion counter

  int grid = segBlocks + L1_BLOCKS + 1;
  hipLaunchKernelGGL(fused_kernel, dim3(grid), dim3(256), 0, stream,
                     logits, params, attn, labels, lengths, P, Bn, segBlocks,
                     counter, nllsum, l1part, segpart, (float*)d_out);
}